// Round 1
// baseline (164.539 us; speedup 1.0000x reference)
//
#include <hip/hip_runtime.h>

typedef __bf16 bf16;
typedef __bf16 bf16x8 __attribute__((ext_vector_type(8)));
typedef float  f32x4  __attribute__((ext_vector_type(4)));

#define MFMA16(a, b, c) __builtin_amdgcn_mfma_f32_16x16x32_bf16((a), (b), (c), 0, 0, 0)

// One block per batch element b. 256 threads = 4 waves; wave w owns k-rows [32w, 32w+32).
// mu/tmsg stored bf16 in LDS with row stride 72 (+16B pad -> conflict-free ds_read_b128).
// base kept in registers in MFMA C-fragment layout. s2/st3 matvecs in fp32 (accuracy trick).
__global__ __launch_bounds__(256, 2)
void qnet_kernel(const float* __restrict__ Xg, const float* __restrict__ Wg,
                 const float* __restrict__ W1g, const float* __restrict__ W2g,
                 const float* __restrict__ W3g, const float* __restrict__ W4g,
                 const float* __restrict__ W5g, const float* __restrict__ W6g,
                 const float* __restrict__ W7g, float* __restrict__ Outg)
{
    __shared__ __align__(16) bf16 muS[128 * 72];   // tmsg, then mu (in-place, k-partitioned per wave)
    __shared__ __align__(16) bf16 W2b[64 * 72];
    __shared__ __align__(16) bf16 W3b[64 * 72];
    __shared__ float W2f[64 * 65];                 // fp32 W2 for the s2 matvec (stride 65: 2-way max)
    __shared__ float partA[4 * 64];
    __shared__ float partB[4 * 64];
    __shared__ float partMu[4 * 64];
    __shared__ float xs[128];
    __shared__ float wws[128];
    __shared__ float W1s[64];
    __shared__ float W4s[64];
    __shared__ float W5s[128];
    __shared__ float sumT[64], st3S[64], sumMu[64], s2S[64], uS[64], pooledS[64];
    __shared__ float qaS;

    const int t    = threadIdx.x;
    const int b    = blockIdx.x;
    const int lane = t & 63;
    const int w    = t >> 6;
    const int l15  = lane & 15;
    const int quad = lane >> 4;

    // ---------------- phase 1: stage inputs/weights ----------------
    if (t < 128) xs[t] = Xg[b * 128 + t];
    else         wws[t - 128] = Wg[b * 128 + (t - 128)];
    if (t < 64)       W1s[t] = W1g[t];
    else if (t < 128) W4s[t - 64] = W4g[t - 64];
    else              W5s[t - 128] = W5g[t - 128];
    {
        const int q = t >> 2, pb = (t & 3) << 4;   // row q, 16-col chunk
        bf16x8 h2a, h2b, h3a, h3b;
#pragma unroll
        for (int i = 0; i < 8; ++i) {
            float a0 = W2g[q * 64 + pb + i], a1 = W2g[q * 64 + pb + 8 + i];
            float c0 = W3g[q * 64 + pb + i], c1 = W3g[q * 64 + pb + 8 + i];
            h2a[i] = (bf16)a0; h2b[i] = (bf16)a1;
            h3a[i] = (bf16)c0; h3b[i] = (bf16)c1;
            W2f[q * 65 + pb + i] = a0; W2f[q * 65 + pb + 8 + i] = a1;
        }
        *(bf16x8*)&W2b[q * 72 + pb]     = h2a;
        *(bf16x8*)&W2b[q * 72 + pb + 8] = h2b;
        *(bf16x8*)&W3b[q * 72 + pb]     = h3a;
        *(bf16x8*)&W3b[q * 72 + pb + 8] = h3b;
    }
    __syncthreads();

    // ---------------- phase 2: tmsg = relu(w*W4) -> bf16, + sum_t partials ----------------
    {
        float s = 0.f;
#pragma unroll 4
        for (int j = 0; j < 32; ++j) {
            const int k = w * 32 + j;
            float v = fmaxf(wws[k] * W4s[lane], 0.f);
            bf16 h = (bf16)v;
            muS[k * 72 + lane] = h;
            s += (float)h;
        }
        partA[w * 64 + lane] = s;
    }
    __syncthreads();
    if (t < 64) sumT[t] = partA[t] + partA[64 + t] + partA[128 + t] + partA[192 + t];
    __syncthreads();

    // ---------------- phase 3: st3 = sum_t @ W3^T (fp32), u = W5b @ W7 ----------------
    {
        float s = 0.f, su = 0.f;
#pragma unroll
        for (int i = 0; i < 16; ++i) {
            const int p = w * 16 + i;
            s  += sumT[p] * W3g[lane * 64 + p];        // st3[q=lane]
            su += W5s[64 + p] * W7g[p * 64 + lane];    // u[p=lane], sum over q-index
        }
        partA[w * 64 + lane] = s;
        partB[w * 64 + lane] = su;
    }
    __syncthreads();
    if (t < 64) {
        st3S[t] = partA[t] + partA[64 + t] + partA[128 + t] + partA[192 + t];
        uS[t]   = partB[t] + partB[64 + t] + partB[128 + t] + partB[192 + t];
    }
    __syncthreads();

    // ---------------- phase 4: GEMM1 (tmsg @ W3b^T), base in regs, mu1 = relu(base) ----------------
    f32x4 acc[2][4];
    float baseR[2][4][4];
    const f32x4 zero4 = {0.f, 0.f, 0.f, 0.f};
    {
        bf16x8 bfr[4][2];
#pragma unroll
        for (int qt = 0; qt < 4; ++qt)
#pragma unroll
            for (int s = 0; s < 2; ++s)
                bfr[qt][s] = *(bf16x8*)&W3b[(qt * 16 + l15) * 72 + s * 32 + quad * 8];
#pragma unroll
        for (int kt = 0; kt < 2; ++kt) {
            const int krow = w * 32 + kt * 16 + l15;
            bf16x8 a0 = *(bf16x8*)&muS[krow * 72 + quad * 8];
            bf16x8 a1 = *(bf16x8*)&muS[krow * 72 + 32 + quad * 8];
#pragma unroll
            for (int qt = 0; qt < 4; ++qt) {
                acc[kt][qt] = MFMA16(a0, bfr[qt][0], zero4);
                acc[kt][qt] = MFMA16(a1, bfr[qt][1], acc[kt][qt]);
            }
        }
        float psum[4] = {0.f, 0.f, 0.f, 0.f};
#pragma unroll
        for (int kt = 0; kt < 2; ++kt)
#pragma unroll
            for (int qt = 0; qt < 4; ++qt)
#pragma unroll
                for (int r = 0; r < 4; ++r) {
                    const int k = w * 32 + kt * 16 + quad * 4 + r;
                    const int q = qt * 16 + l15;
                    float bb = xs[k] * W1s[q] + st3S[q] - acc[kt][qt][r];
                    baseR[kt][qt][r] = bb;
                    bf16 h = (bf16)fmaxf(bb, 0.f);
                    muS[k * 72 + q] = h;
                    psum[qt] += (float)h;
                }
#pragma unroll
        for (int qt = 0; qt < 4; ++qt) {
            float p = psum[qt];
            p += __shfl_xor(p, 16);
            p += __shfl_xor(p, 32);
            if (lane < 16) partMu[w * 64 + qt * 16 + lane] = p;
        }
    }
    __syncthreads();

    // ---------------- phase 5: 3 message-passing iterations ----------------
    bf16x8 bW2[4][2];
#pragma unroll
    for (int qt = 0; qt < 4; ++qt)
#pragma unroll
        for (int s = 0; s < 2; ++s)
            bW2[qt][s] = *(bf16x8*)&W2b[(qt * 16 + l15) * 72 + s * 32 + quad * 8];

    for (int it = 0; it < 3; ++it) {
        if (t < 64) sumMu[t] = partMu[t] + partMu[64 + t] + partMu[128 + t] + partMu[192 + t];
        __syncthreads();
        {
            float s = 0.f;
#pragma unroll
            for (int i = 0; i < 16; ++i) {
                const int p = w * 16 + i;
                s += sumMu[p] * W2f[lane * 65 + p];    // s2[q=lane] in fp32
            }
            partA[w * 64 + lane] = s;
        }
        __syncthreads();
        if (t < 64) s2S[t] = partA[t] + partA[64 + t] + partA[128 + t] + partA[192 + t];
        __syncthreads();

#pragma unroll
        for (int kt = 0; kt < 2; ++kt) {
            const int krow = w * 32 + kt * 16 + l15;
            bf16x8 a0 = *(bf16x8*)&muS[krow * 72 + quad * 8];
            bf16x8 a1 = *(bf16x8*)&muS[krow * 72 + 32 + quad * 8];
#pragma unroll
            for (int qt = 0; qt < 4; ++qt) {
                acc[kt][qt] = MFMA16(a0, bW2[qt][0], zero4);
                acc[kt][qt] = MFMA16(a1, bW2[qt][1], acc[kt][qt]);
            }
        }
        float psum[4] = {0.f, 0.f, 0.f, 0.f};
#pragma unroll
        for (int kt = 0; kt < 2; ++kt)
#pragma unroll
            for (int qt = 0; qt < 4; ++qt)
#pragma unroll
                for (int r = 0; r < 4; ++r) {
                    const int k = w * 32 + kt * 16 + quad * 4 + r;
                    const int q = qt * 16 + l15;
                    float v = fmaxf(baseR[kt][qt][r] + s2S[q] - acc[kt][qt][r], 0.f);
                    bf16 h = (bf16)v;
                    muS[k * 72 + q] = h;
                    psum[qt] += (float)h;
                }
#pragma unroll
        for (int qt = 0; qt < 4; ++qt) {
            float p = psum[qt];
            p += __shfl_xor(p, 16);
            p += __shfl_xor(p, 32);
            if (lane < 16) partMu[w * 64 + qt * 16 + lane] = p;
        }
        __syncthreads();
    }

    // ---------------- phase 6: pooled readout + output ----------------
    if (t < 64) sumMu[t] = partMu[t] + partMu[64 + t] + partMu[128 + t] + partMu[192 + t];
    __syncthreads();
    {
        float s = 0.f;
#pragma unroll
        for (int i = 0; i < 16; ++i) {
            const int p = w * 16 + i;
            s += sumMu[p] * W6g[lane * 64 + p];        // pooled[q=lane] partial
        }
        partA[w * 64 + lane] = s;
    }
    __syncthreads();
    if (t < 64) pooledS[t] = fmaxf(partA[t] + partA[64 + t] + partA[128 + t] + partA[192 + t], 0.f);
    __syncthreads();
    if (t < 64) {
        float v = pooledS[t] * W5s[t];
#pragma unroll
        for (int m = 32; m >= 1; m >>= 1) v += __shfl_xor(v, m);
        if (t == 0) qaS = v;
    }
    __syncthreads();
    if (t < 128) {
        float accq = qaS;
#pragma unroll
        for (int j = 0; j < 8; ++j) {
            bf16x8 m8 = *(bf16x8*)&muS[t * 72 + j * 8];
#pragma unroll
            for (int e = 0; e < 8; ++e) accq += (float)m8[e] * uS[j * 8 + e];
        }
        Outg[b * 128 + t] = accq;
    }
}

extern "C" void kernel_launch(void* const* d_in, const int* in_sizes, int n_in,
                              void* d_out, int out_size, void* d_ws, size_t ws_size,
                              hipStream_t stream) {
    (void)n_in; (void)d_ws; (void)ws_size; (void)out_size;
    const int B = in_sizes[0] >> 7;   // 4096
    qnet_kernel<<<B, 256, 0, stream>>>(
        (const float*)d_in[0], (const float*)d_in[1], (const float*)d_in[2],
        (const float*)d_in[3], (const float*)d_in[4], (const float*)d_in[5],
        (const float*)d_in[6], (const float*)d_in[7], (const float*)d_in[8],
        (float*)d_out);
}